// Round 11
// baseline (351.877 us; speedup 1.0000x reference)
//
#include <hip/hip_runtime.h>
#include <cmath>
#include <cfloat>

#define HW_ 16384

__device__ __forceinline__ unsigned f2key(float f){
    unsigned u = __float_as_uint(f);
    return u ^ ((u & 0x80000000u) ? 0xFFFFFFFFu : 0x80000000u);
}
__device__ __forceinline__ float key2f(unsigned k){
    unsigned u = (k & 0x80000000u) ? (k ^ 0x80000000u) : ~k;
    return __uint_as_float(u);
}
__device__ __forceinline__ unsigned short f2bf(float f){
    unsigned u = __float_as_uint(f);
    unsigned r = u + 0x7FFFu + ((u >> 16) & 1u);
    return (unsigned short)(r >> 16);
}
__device__ __forceinline__ float bf2f(unsigned short s){
    return __uint_as_float((unsigned)s << 16);
}
// packed helpers (bf16 pairs in u32; all pooled values >= 0 so u16 order == float order)
__device__ __forceinline__ unsigned pkmax(unsigned a, unsigned b){
    unsigned d;
    asm("v_pk_max_u16 %0, %1, %2" : "=v"(d) : "v"(a), "v"(b));
    return d;
}
__device__ __forceinline__ unsigned alignb(unsigned hi, unsigned lo){
    unsigned d;
    asm("v_alignbit_b32 %0, %1, %2, 16" : "=v"(d) : "v"(hi), "v"(lo));
    return d;
}
__device__ __forceinline__ unsigned cvtpk(float lo, float hi){
    unsigned d;
    asm("v_cvt_pk_bf16_f32 %0, %1, %2" : "=v"(d) : "v"(lo), "v"(hi));
    return d;
}
__device__ __forceinline__ unsigned wscan_incl(unsigned v, int lane){
    #pragma unroll
    for (int o = 1; o < 64; o <<= 1){
        unsigned u = __shfl_up(v, o);
        v += (lane >= o) ? u : 0u;
    }
    return v;
}

// MFMA types
typedef short bf16x8 __attribute__((ext_vector_type(8)));
typedef float f32x4  __attribute__((ext_vector_type(4)));
__device__ __forceinline__ bf16x8 tofrag(uint4 q){
    union { uint4 q; bf16x8 f; } u; u.q = q; return u.f;
}

// ============================ K0: weight hi/lo split (runs once) ============================
__global__ __launch_bounds__(256) void k0_split(
    const float* __restrict__ w1, const float* __restrict__ w2,
    unsigned short* __restrict__ W1h, unsigned short* __restrict__ W1l,
    unsigned short* __restrict__ W2h, unsigned short* __restrict__ W2l)
{
    int e = blockIdx.x * 256 + threadIdx.x;   // 0..8191
    if (e < 4096){
        float f = w1[e];                       // [16][256] row-major
        unsigned short hi = f2bf(f);
        W1h[e] = hi;
        W1l[e] = f2bf(f - bf2f(hi));
    } else {
        int e2 = e - 4096;
        float f = w2[e2];                      // [256][16] row-major
        unsigned short hi = f2bf(f);
        W2h[e2] = hi;
        W2l[e2] = f2bf(f - bf2f(hi));
    }
}

// ============================ K1f (unchanged from R8) ============================
__global__ __launch_bounds__(512, 6) void k1f(
    const float* __restrict__ x,
    unsigned short* __restrict__ outp, unsigned short* __restrict__ m64g,
    float g1, float q2, float q3, float q4, float q5, float q6)
{
    __shared__ __align__(16) unsigned short C0[16384];
    __shared__ __align__(16) unsigned short H5s[8192];
    __shared__ unsigned hist[1024];
    __shared__ unsigned wsum[8];
    __shared__ unsigned redA[8], redB[8];
    __shared__ unsigned s_dA, s_dB, s_cloA, s_cloB, s_keyA, s_keyB;

    const int tid = threadIdx.x;
    const int lane = tid & 63;
    const int wid = tid >> 6;
    const unsigned bc = blockIdx.x;
    const float4* xp4 = (const float4*)(x + (size_t)bc * HW_);

    unsigned key[32];

    #pragma unroll
    for (int k = 0; k < 2; ++k) hist[tid + k * 512] = 0u;
    __syncthreads();
    #pragma unroll
    for (int k = 0; k < 8; ++k){
        float4 v = xp4[tid + k * 512];
        key[4*k+0] = f2key(v.x);
        key[4*k+1] = f2key(v.y);
        key[4*k+2] = f2key(v.z);
        key[4*k+3] = f2key(v.w);
        atomicAdd(&hist[key[4*k+0] >> 22], 1u);
        atomicAdd(&hist[key[4*k+1] >> 22], 1u);
        atomicAdd(&hist[key[4*k+2] >> 22], 1u);
        atomicAdd(&hist[key[4*k+3] >> 22], 1u);
    }
    __syncthreads();

    unsigned rA = 15563u, rB = 15564u;
    unsigned prefVal = 0u, prefMask = 0u;
    bool done = false;

    {
        unsigned part = hist[tid*2] + hist[tid*2+1];
        unsigned incl = wscan_incl(part, lane);
        if (lane == 63) wsum[wid] = incl;
        __syncthreads();
        unsigned off = 0;
        #pragma unroll
        for (int w = 0; w < 8; ++w) off += (w < wid) ? wsum[w] : 0u;
        unsigned phi = incl + off;
        unsigned plo = phi - part;
        if (rA >= plo && rA < phi){
            unsigned c = plo;
            #pragma unroll
            for (int k = 0; k < 2; ++k){
                unsigned hh = hist[tid*2+k];
                if (rA < c + hh){ s_dA = tid*2+k; s_cloA = c; break; }
                c += hh;
            }
        }
        if (rB >= plo && rB < phi){
            unsigned c = plo;
            #pragma unroll
            for (int k = 0; k < 2; ++k){
                unsigned hh = hist[tid*2+k];
                if (rB < c + hh){ s_dB = tid*2+k; s_cloB = c; break; }
                c += hh;
            }
        }
        __syncthreads();
        unsigned dA = s_dA, dB = s_dB;
        if (dA != dB){
            unsigned locA = 0u, locB = 0xFFFFFFFFu;
            #pragma unroll
            for (int e = 0; e < 32; ++e){
                unsigned d = key[e] >> 22;
                if (d == dA) locA = max(locA, key[e]);
                if (d == dB) locB = min(locB, key[e]);
            }
            #pragma unroll
            for (int o = 32; o > 0; o >>= 1){
                locA = max(locA, __shfl_down(locA, o));
                locB = min(locB, __shfl_down(locB, o));
            }
            if (lane == 0){ redA[wid] = locA; redB[wid] = locB; }
            __syncthreads();
            if (tid == 0){
                unsigned a = redA[0], b = redB[0];
                for (int w = 1; w < 8; ++w){ a = max(a, redA[w]); b = min(b, redB[w]); }
                s_keyA = a; s_keyB = b;
            }
            __syncthreads();
            done = true;
        } else {
            prefVal = dA << 22; prefMask = 0x3FFu << 22;
            rA -= s_cloA; rB -= s_cloB;
            __syncthreads();
        }
    }

    if (!done){
        const int shifts[3] = {14, 6, 0};
        const int bitsv[3]  = {8, 8, 6};
        for (int lvl = 0; lvl < 3 && !done; ++lvl){
            int shift = shifts[lvl];
            unsigned nb = 1u << bitsv[lvl];
            unsigned msk = nb - 1u;
            if (tid < (int)nb) hist[tid] = 0u;
            __syncthreads();
            #pragma unroll
            for (int e = 0; e < 32; ++e){
                if ((key[e] & prefMask) == prefVal)
                    atomicAdd(&hist[(key[e] >> shift) & msk], 1u);
            }
            __syncthreads();
            unsigned part = (tid < (int)nb) ? hist[tid] : 0u;
            unsigned incl = wscan_incl(part, lane);
            if (lane == 63) wsum[wid] = incl;
            __syncthreads();
            unsigned off = 0;
            #pragma unroll
            for (int w = 0; w < 8; ++w) off += (w < wid) ? wsum[w] : 0u;
            unsigned phi = incl + off;
            unsigned plo = phi - part;
            if (tid < (int)nb){
                if (rA >= plo && rA < phi){ s_dA = tid; s_cloA = plo; }
                if (rB >= plo && rB < phi){ s_dB = tid; s_cloB = plo; }
            }
            __syncthreads();
            unsigned dA = s_dA, dB = s_dB;
            if (dA != dB){
                unsigned mA = prefMask | (msk << shift);
                unsigned vAp = prefVal | (dA << shift);
                unsigned vBp = prefVal | (dB << shift);
                unsigned locA = 0u, locB = 0xFFFFFFFFu;
                #pragma unroll
                for (int e = 0; e < 32; ++e){
                    if ((key[e] & mA) == vAp) locA = max(locA, key[e]);
                    if ((key[e] & mA) == vBp) locB = min(locB, key[e]);
                }
                #pragma unroll
                for (int o = 32; o > 0; o >>= 1){
                    locA = max(locA, __shfl_down(locA, o));
                    locB = min(locB, __shfl_down(locB, o));
                }
                if (lane == 0){ redA[wid] = locA; redB[wid] = locB; }
                __syncthreads();
                if (tid == 0){
                    unsigned a = redA[0], b = redB[0];
                    for (int w = 1; w < 8; ++w){ a = max(a, redA[w]); b = min(b, redB[w]); }
                    s_keyA = a; s_keyB = b;
                }
                __syncthreads();
                done = true;
            } else {
                prefVal |= dA << shift;
                prefMask |= msk << shift;
                rA -= s_cloA; rB -= s_cloB;
                if (lvl == 2){
                    if (tid == 0){ s_keyA = prefVal; s_keyB = prefVal; }
                    done = true;
                }
                __syncthreads();
            }
        }
    }

    float vlo = key2f(s_keyA);
    float vhi = key2f(s_keyB);
    float idxq = 0.95f * 16383.0f;
    float frac = idxq - floorf(idxq);
    const float thr = vlo * (1.0f - frac) + vhi * frac;

    #pragma unroll
    for (int k = 0; k < 8; ++k){
        int i = tid + k * 512;
        float f0 = key2f(key[4*k+0]); f0 = (f0 >= thr) ? f0 : 0.0f;
        float f1 = key2f(key[4*k+1]); f1 = (f1 >= thr) ? f1 : 0.0f;
        float f2 = key2f(key[4*k+2]); f2 = (f2 >= thr) ? f2 : 0.0f;
        float f3 = key2f(key[4*k+3]); f3 = (f3 >= thr) ? f3 : 0.0f;
        uint2 w; w.x = cvtpk(f0, f1); w.y = cvtpk(f2, f3);
        ((uint2*)C0)[i] = w;
    }
    __syncthreads();

    {
        const unsigned* C0w = (const unsigned*)C0;
        unsigned* outp32 = (unsigned*)(outp + (size_t)bc * HW_);
        const int wc = lane;
        const int r0 = wid * 16;

        unsigned hmA, hmB, hmC, cB, cC;
        {
            int r = r0 - 1;
            if (r < 0){ hmA = 0u; }
            else {
                unsigned w = C0w[r*64 + wc];
                unsigned wl = __shfl_up(w, 1);
                unsigned wr = __shfl_down(w, 1);
                if (wc == 0)  wl = 0u;
                if (wc == 63) wr = 0u;
                hmA = pkmax(pkmax(alignb(w, wl), w), alignb(wr, w));
            }
        }
        {
            int r = r0;
            unsigned w = C0w[r*64 + wc];
            unsigned wl = __shfl_up(w, 1);
            unsigned wr = __shfl_down(w, 1);
            if (wc == 0)  wl = 0u;
            if (wc == 63) wr = 0u;
            hmB = pkmax(pkmax(alignb(w, wl), w), alignb(wr, w));
            cB = w;
        }
        #pragma unroll
        for (int rr = 0; rr < 16; ++rr){
            int r = r0 + rr;
            {
                int rn = r + 1;
                if (rn > 127){ hmC = 0u; cC = 0u; }
                else {
                    unsigned w = C0w[rn*64 + wc];
                    unsigned wl = __shfl_up(w, 1);
                    unsigned wr = __shfl_down(w, 1);
                    if (wc == 0)  wl = 0u;
                    if (wc == 63) wr = 0u;
                    hmC = pkmax(pkmax(alignb(w, wl), w), alignb(wr, w));
                    cC = w;
                }
            }
            unsigned p1 = pkmax(pkmax(hmA, hmB), hmC);
            float a0 = g1 * bf2f((unsigned short)(p1 & 0xFFFFu));
            float a1v = g1 * bf2f((unsigned short)(p1 >> 16));
            outp32[r*64 + wc] = pkmax(cB, cvtpk(a0, a1v));
            unsigned wjm1 = __shfl_up(p1, 1);
            unsigned wjp1 = __shfl_down(p1, 1);
            if (wc == 0)  wjm1 = 0u;
            if (wc == 63) wjp1 = 0u;
            unsigned s = pkmax(wjm1, p1);
            s = pkmax(s, s >> 16);
            s = pkmax(s, wjp1 & 0xFFFFu);
            H5s[r*64 + wc] = (unsigned short)s;
            hmA = hmB; hmB = hmC; cB = cC;
        }
    }
    __syncthreads();

    unsigned* U = (unsigned*)C0;
    unsigned* T = ((unsigned*)C0) + 2048;
    float mf[8];
    #pragma unroll
    for (int k = 0; k < 4; ++k){
        int q = tid + k * 512;
        int i = q >> 5, wj = q & 31;
        int rr = 2 * i;
        const unsigned* H5w = (const unsigned*)H5s;
        unsigned m = pkmax(H5w[rr*32 + wj], H5w[(rr+1)*32 + wj]);
        if (rr >= 1) m = pkmax(m, H5w[(rr-1)*32 + wj]);
        if (rr >= 2) m = pkmax(m, H5w[(rr-2)*32 + wj]);
        if (rr + 2 <= 127) m = pkmax(m, H5w[(rr+2)*32 + wj]);
        U[q] = m;
        mf[2*k]   = q2 * bf2f((unsigned short)(m & 0xFFFFu));
        mf[2*k+1] = q2 * bf2f((unsigned short)(m >> 16));
    }
    __syncthreads();

    const float gs[4] = {q3, q4, q5, q6};
    #pragma unroll
    for (int it = 0; it < 4; ++it){
        #pragma unroll
        for (int k = 0; k < 4; ++k){
            int q = tid + k * 512;
            unsigned w = U[q];
            unsigned wl = __shfl_up(w, 1);
            unsigned wr = __shfl_down(w, 1);
            if ((q & 31) == 0)  wl = 0u;
            if ((q & 31) == 31) wr = 0u;
            T[q] = pkmax(pkmax(alignb(w, wl), w), alignb(wr, w));
        }
        __syncthreads();
        #pragma unroll
        for (int k = 0; k < 4; ++k){
            int q = tid + k * 512;
            int r = q >> 5;
            unsigned w = T[q];
            if (r > 0)  w = pkmax(w, T[q - 32]);
            if (r < 63) w = pkmax(w, T[q + 32]);
            U[q] = w;
            mf[2*k]   = fmaxf(mf[2*k],   gs[it] * bf2f((unsigned short)(w & 0xFFFFu)));
            mf[2*k+1] = fmaxf(mf[2*k+1], gs[it] * bf2f((unsigned short)(w >> 16)));
        }
        __syncthreads();
    }

    {
        unsigned* mp = (unsigned*)(m64g + (size_t)bc * 4096);
        #pragma unroll
        for (int k = 0; k < 4; ++k){
            int q = tid + k * 512;
            mp[q] = cvtpk(mf[2*k], mf[2*k+1]);
        }
    }
}

// ============================ K3: MFMA MLP v3 ============================
// 64 px/block, 256 thr = 4 waves (wave w -> px [w*16, w*16+16)).
// LDS = SOUT 32KB only -> 5 blocks/CU. One barrier total.
// GEMM1: D1[mid][px] = (W1h+W1l) x out'. h redistributed via shuffles (no LDS).
// GEMM2 transposed: D2[px][ch] = P[px][mid] x W2^T[mid][ch]
//   -> thread holds 4 consecutive px for one ch -> float4 x-load / y-store.
__global__ __launch_bounds__(256, 5) void k3_mfma(
    const float* __restrict__ x,
    const unsigned short* __restrict__ outp, const unsigned short* __restrict__ m64,
    const unsigned short* __restrict__ W1h, const unsigned short* __restrict__ W1l,
    const unsigned short* __restrict__ W2h, const unsigned short* __restrict__ W2l,
    const float* __restrict__ b1, const float* __restrict__ b2,
    float* __restrict__ y)
{
    __shared__ __align__(16) unsigned SOUT32[8192];   // [64px][128 ch-pair words], swizzled

    const int tid  = threadIdx.x;
    const int lane = tid & 63;
    const int wid  = tid >> 6;
    const int blk  = blockIdx.x;
    const int b    = blk >> 8;
    const int px0  = (blk & 255) * 64;

    // ---- stage out' = max(outp, m64up): repack channel-pairs per px, swizzled ----
    {
        const int row = px0 >> 7;
        const int mibase = (row >> 1)*64 + ((px0 & 127) >> 1);
        const unsigned* op32 = (const unsigned*)(outp + (size_t)b*256*HW_);
        const unsigned short* mp = m64 + (size_t)b*256*4096;
        #pragma unroll
        for (int i = 0; i < 16; ++i){
            int u = i*256 + tid;
            int c4 = u >> 5, pxp = u & 31;       // c4: ch pair 0..127, pxp: px pair 0..31
            int ch0 = 2*c4;
            unsigned wA = op32[ch0*(HW_/2) + px0/2 + pxp];
            unsigned wB = op32[(ch0+1)*(HW_/2) + px0/2 + pxp];
            unsigned mA = (unsigned)mp[ch0*4096 + mibase + pxp] * 0x10001u;
            unsigned mB = (unsigned)mp[(ch0+1)*4096 + mibase + pxp] * 0x10001u;
            unsigned va = pkmax(wA, mA);
            unsigned vb = pkmax(wB, mB);
            unsigned wpa = (va & 0xFFFFu) | (vb << 16);        // (ch0,ch1) @ even px
            unsigned wpb = (va >> 16) | (vb & 0xFFFF0000u);    // (ch0,ch1) @ odd px
            int sw = (pxp & 7) << 2;
            SOUT32[(2*pxp)  *128 + (c4 ^ sw)] = wpa;
            SOUT32[(2*pxp+1)*128 + (c4 ^ sw)] = wpb;
        }
    }
    __syncthreads();

    const int nidx = lane & 15;
    const int kg   = lane >> 4;
    const int px_t = wid*16 + nidx;
    const int sxz  = ((px_t >> 1) & 7) << 2;

    // ---- GEMM1: D1[mid][px] = (W1hi+W1lo) x out' ----
    f32x4 acc = {0.f, 0.f, 0.f, 0.f};
    #pragma unroll
    for (int ks = 0; ks < 8; ++ks){
        int w0 = (ks*16 + kg*4) ^ sxz;
        bf16x8 fb = tofrag(*(const uint4*)&SOUT32[px_t*128 + w0]);
        bf16x8 ah = tofrag(*(const uint4*)(W1h + nidx*256 + ks*32 + kg*8));
        bf16x8 al = tofrag(*(const uint4*)(W1l + nidx*256 + ks*32 + kg*8));
        acc = __builtin_amdgcn_mfma_f32_16x16x32_bf16(ah, fb, acc, 0, 0, 0);
        acc = __builtin_amdgcn_mfma_f32_16x16x32_bf16(al, fb, acc, 0, 0, 0);
    }

    // ---- relu + bias; hi/lo split; pack to bf16 pairs (this thread: mids kg*4..+4, px=nidx) ----
    float h0 = fmaxf(acc[0] + b1[kg*4 + 0], 0.0f);
    float h1 = fmaxf(acc[1] + b1[kg*4 + 1], 0.0f);
    float h2 = fmaxf(acc[2] + b1[kg*4 + 2], 0.0f);
    float h3 = fmaxf(acc[3] + b1[kg*4 + 3], 0.0f);
    unsigned short e0 = f2bf(h0), e1 = f2bf(h1), e2 = f2bf(h2), e3 = f2bf(h3);
    unsigned Wh0 = (unsigned)e0 | ((unsigned)e1 << 16);
    unsigned Wh1 = (unsigned)e2 | ((unsigned)e3 << 16);
    unsigned Wl0 = cvtpk(h0 - bf2f(e0), h1 - bf2f(e1));
    unsigned Wl1 = cvtpk(h2 - bf2f(e2), h3 - bf2f(e3));

    // ---- A2 frags via shuffle: row px = nidx, k = mids kg*8..+8 (kg<2), else 0 ----
    int s0 = ((kg & 1) << 5) + nidx;      // lane holding mids kslice..+4 for px=nidx
    int s1 = s0 + 16;
    unsigned ah0 = (unsigned)__shfl((int)Wh0, s0);
    unsigned ah1 = (unsigned)__shfl((int)Wh1, s0);
    unsigned ah2 = (unsigned)__shfl((int)Wh0, s1);
    unsigned ah3 = (unsigned)__shfl((int)Wh1, s1);
    unsigned bl0 = (unsigned)__shfl((int)Wl0, s0);
    unsigned bl1 = (unsigned)__shfl((int)Wl1, s0);
    unsigned bl2 = (unsigned)__shfl((int)Wl0, s1);
    unsigned bl3 = (unsigned)__shfl((int)Wl1, s1);
    const bool act = (kg < 2);
    uint4 qah = act ? (uint4){ah0, ah1, ah2, ah3} : (uint4){0u,0u,0u,0u};
    uint4 qal = act ? (uint4){bl0, bl1, bl2, bl3} : (uint4){0u,0u,0u,0u};
    bf16x8 A2h = tofrag(qah), A2l = tofrag(qal);

    // ---- GEMM2 (transposed) + float4 epilogue per 16-channel tile ----
    #pragma unroll 4
    for (int t = 0; t < 16; ++t){
        uint4 qbh = {0u,0u,0u,0u}, qbl = {0u,0u,0u,0u};
        if (act){
            qbh = *(const uint4*)(W2h + (t*16 + nidx)*16 + kg*8);
            qbl = *(const uint4*)(W2l + (t*16 + nidx)*16 + kg*8);
        }
        f32x4 d2 = {0.f, 0.f, 0.f, 0.f};
        d2 = __builtin_amdgcn_mfma_f32_16x16x32_bf16(A2h, tofrag(qbh), d2, 0, 0, 0);
        d2 = __builtin_amdgcn_mfma_f32_16x16x32_bf16(A2l, tofrag(qbh), d2, 0, 0, 0);
        d2 = __builtin_amdgcn_mfma_f32_16x16x32_bf16(A2h, tofrag(qbl), d2, 0, 0, 0);
        // D2: col = ch = nidx (within tile), rows px = kg*4 + i2 (consecutive!)
        int ch = t*16 + nidx;
        float bias = b2[ch];
        size_t rowbase = ((size_t)(b*256 + ch))*HW_ + px0 + wid*16 + kg*4;
        float4 xv = *(const float4*)&x[rowbase];
        float4 yv;
        yv.x = xv.x * (1.0f / (1.0f + __expf(-(d2[0] + bias))));
        yv.y = xv.y * (1.0f / (1.0f + __expf(-(d2[1] + bias))));
        yv.z = xv.z * (1.0f / (1.0f + __expf(-(d2[2] + bias))));
        yv.w = xv.w * (1.0f / (1.0f + __expf(-(d2[3] + bias))));
        *(float4*)&y[rowbase] = yv;
    }
}

extern "C" void kernel_launch(void* const* d_in, const int* in_sizes, int n_in,
                              void* d_out, int out_size, void* d_ws, size_t ws_size,
                              hipStream_t stream) {
    const float* x  = (const float*)d_in[0];
    const float* w1 = (const float*)d_in[1];
    const float* b1 = (const float*)d_in[2];
    const float* w2 = (const float*)d_in[3];
    const float* b2 = (const float*)d_in[4];
    float* y  = (float*)d_out;
    char* ws = (char*)d_ws;

    unsigned short* outp = (unsigned short*)ws;                 // 134 MB
    unsigned short* m64  = (unsigned short*)(ws + 134217728);   // 33.5 MB
    unsigned short* W1h  = (unsigned short*)(ws + 167772160);
    unsigned short* W1l  = W1h + 4096;
    unsigned short* W2h  = W1h + 8192;
    unsigned short* W2l  = W1h + 12288;

    float g1 = 0.99f;
    float q2 = (float)std::pow(0.99, 3.0);
    float q3 = (float)std::pow(0.99, 7.0);
    float q4 = (float)std::pow(0.99, 15.0);
    float q5 = (float)std::pow(0.99, 31.0);
    float q6 = (float)std::pow(0.99, 63.0);

    k0_split<<<32, 256, 0, stream>>>(w1, w2, W1h, W1l, W2h, W2l);
    k1f<<<4096, 512, 0, stream>>>(x, outp, m64, g1, q2, q3, q4, q5, q6);
    k3_mfma<<<4096, 256, 0, stream>>>(x, outp, m64, W1h, W1l, W2h, W2l, b1, b2, y);
}

// Round 12
// 349.907 us; speedup vs baseline: 1.0056x; 1.0056x over previous
//
#include <hip/hip_runtime.h>
#include <cmath>
#include <cfloat>

#define HW_ 16384

__device__ __forceinline__ unsigned f2key(float f){
    unsigned u = __float_as_uint(f);
    return u ^ ((u & 0x80000000u) ? 0xFFFFFFFFu : 0x80000000u);
}
__device__ __forceinline__ float key2f(unsigned k){
    unsigned u = (k & 0x80000000u) ? (k ^ 0x80000000u) : ~k;
    return __uint_as_float(u);
}
__device__ __forceinline__ unsigned short f2bf(float f){
    unsigned u = __float_as_uint(f);
    unsigned r = u + 0x7FFFu + ((u >> 16) & 1u);
    return (unsigned short)(r >> 16);
}
__device__ __forceinline__ float bf2f(unsigned short s){
    return __uint_as_float((unsigned)s << 16);
}
// packed helpers (bf16 pairs in u32; all pooled values >= 0 so u16 order == float order)
__device__ __forceinline__ unsigned pkmax(unsigned a, unsigned b){
    unsigned d;
    asm("v_pk_max_u16 %0, %1, %2" : "=v"(d) : "v"(a), "v"(b));
    return d;
}
__device__ __forceinline__ unsigned alignb(unsigned hi, unsigned lo){
    unsigned d;
    asm("v_alignbit_b32 %0, %1, %2, 16" : "=v"(d) : "v"(hi), "v"(lo));
    return d;
}
__device__ __forceinline__ unsigned cvtpk(float lo, float hi){
    unsigned d;
    asm("v_cvt_pk_bf16_f32 %0, %1, %2" : "=v"(d) : "v"(lo), "v"(hi));
    return d;
}
__device__ __forceinline__ unsigned wscan_incl(unsigned v, int lane){
    #pragma unroll
    for (int o = 1; o < 64; o <<= 1){
        unsigned u = __shfl_up(v, o);
        v += (lane >= o) ? u : 0u;
    }
    return v;
}

// MFMA types
typedef short bf16x8 __attribute__((ext_vector_type(8)));
typedef float f32x4  __attribute__((ext_vector_type(4)));
__device__ __forceinline__ bf16x8 tofrag(uint4 q){
    union { uint4 q; bf16x8 f; } u; u.q = q; return u.f;
}

// ============================ K0: weight hi/lo split (runs once) ============================
__global__ __launch_bounds__(256) void k0_split(
    const float* __restrict__ w1, const float* __restrict__ w2,
    unsigned short* __restrict__ W1h, unsigned short* __restrict__ W1l,
    unsigned short* __restrict__ W2h, unsigned short* __restrict__ W2l)
{
    int e = blockIdx.x * 256 + threadIdx.x;   // 0..8191
    if (e < 4096){
        float f = w1[e];                       // [16][256] row-major
        unsigned short hi = f2bf(f);
        W1h[e] = hi;
        W1l[e] = f2bf(f - bf2f(hi));
    } else {
        int e2 = e - 4096;
        float f = w2[e2];                      // [256][16] row-major
        unsigned short hi = f2bf(f);
        W2h[e2] = hi;
        W2l[e2] = f2bf(f - bf2f(hi));
    }
}

// ============================ K1f (unchanged from R8) ============================
__global__ __launch_bounds__(512, 6) void k1f(
    const float* __restrict__ x,
    unsigned short* __restrict__ outp, unsigned short* __restrict__ m64g,
    float g1, float q2, float q3, float q4, float q5, float q6)
{
    __shared__ __align__(16) unsigned short C0[16384];
    __shared__ __align__(16) unsigned short H5s[8192];
    __shared__ unsigned hist[1024];
    __shared__ unsigned wsum[8];
    __shared__ unsigned redA[8], redB[8];
    __shared__ unsigned s_dA, s_dB, s_cloA, s_cloB, s_keyA, s_keyB;

    const int tid = threadIdx.x;
    const int lane = tid & 63;
    const int wid = tid >> 6;
    const unsigned bc = blockIdx.x;
    const float4* xp4 = (const float4*)(x + (size_t)bc * HW_);

    unsigned key[32];

    #pragma unroll
    for (int k = 0; k < 2; ++k) hist[tid + k * 512] = 0u;
    __syncthreads();
    #pragma unroll
    for (int k = 0; k < 8; ++k){
        float4 v = xp4[tid + k * 512];
        key[4*k+0] = f2key(v.x);
        key[4*k+1] = f2key(v.y);
        key[4*k+2] = f2key(v.z);
        key[4*k+3] = f2key(v.w);
        atomicAdd(&hist[key[4*k+0] >> 22], 1u);
        atomicAdd(&hist[key[4*k+1] >> 22], 1u);
        atomicAdd(&hist[key[4*k+2] >> 22], 1u);
        atomicAdd(&hist[key[4*k+3] >> 22], 1u);
    }
    __syncthreads();

    unsigned rA = 15563u, rB = 15564u;
    unsigned prefVal = 0u, prefMask = 0u;
    bool done = false;

    {
        unsigned part = hist[tid*2] + hist[tid*2+1];
        unsigned incl = wscan_incl(part, lane);
        if (lane == 63) wsum[wid] = incl;
        __syncthreads();
        unsigned off = 0;
        #pragma unroll
        for (int w = 0; w < 8; ++w) off += (w < wid) ? wsum[w] : 0u;
        unsigned phi = incl + off;
        unsigned plo = phi - part;
        if (rA >= plo && rA < phi){
            unsigned c = plo;
            #pragma unroll
            for (int k = 0; k < 2; ++k){
                unsigned hh = hist[tid*2+k];
                if (rA < c + hh){ s_dA = tid*2+k; s_cloA = c; break; }
                c += hh;
            }
        }
        if (rB >= plo && rB < phi){
            unsigned c = plo;
            #pragma unroll
            for (int k = 0; k < 2; ++k){
                unsigned hh = hist[tid*2+k];
                if (rB < c + hh){ s_dB = tid*2+k; s_cloB = c; break; }
                c += hh;
            }
        }
        __syncthreads();
        unsigned dA = s_dA, dB = s_dB;
        if (dA != dB){
            unsigned locA = 0u, locB = 0xFFFFFFFFu;
            #pragma unroll
            for (int e = 0; e < 32; ++e){
                unsigned d = key[e] >> 22;
                if (d == dA) locA = max(locA, key[e]);
                if (d == dB) locB = min(locB, key[e]);
            }
            #pragma unroll
            for (int o = 32; o > 0; o >>= 1){
                locA = max(locA, __shfl_down(locA, o));
                locB = min(locB, __shfl_down(locB, o));
            }
            if (lane == 0){ redA[wid] = locA; redB[wid] = locB; }
            __syncthreads();
            if (tid == 0){
                unsigned a = redA[0], b = redB[0];
                for (int w = 1; w < 8; ++w){ a = max(a, redA[w]); b = min(b, redB[w]); }
                s_keyA = a; s_keyB = b;
            }
            __syncthreads();
            done = true;
        } else {
            prefVal = dA << 22; prefMask = 0x3FFu << 22;
            rA -= s_cloA; rB -= s_cloB;
            __syncthreads();
        }
    }

    if (!done){
        const int shifts[3] = {14, 6, 0};
        const int bitsv[3]  = {8, 8, 6};
        for (int lvl = 0; lvl < 3 && !done; ++lvl){
            int shift = shifts[lvl];
            unsigned nb = 1u << bitsv[lvl];
            unsigned msk = nb - 1u;
            if (tid < (int)nb) hist[tid] = 0u;
            __syncthreads();
            #pragma unroll
            for (int e = 0; e < 32; ++e){
                if ((key[e] & prefMask) == prefVal)
                    atomicAdd(&hist[(key[e] >> shift) & msk], 1u);
            }
            __syncthreads();
            unsigned part = (tid < (int)nb) ? hist[tid] : 0u;
            unsigned incl = wscan_incl(part, lane);
            if (lane == 63) wsum[wid] = incl;
            __syncthreads();
            unsigned off = 0;
            #pragma unroll
            for (int w = 0; w < 8; ++w) off += (w < wid) ? wsum[w] : 0u;
            unsigned phi = incl + off;
            unsigned plo = phi - part;
            if (tid < (int)nb){
                if (rA >= plo && rA < phi){ s_dA = tid; s_cloA = plo; }
                if (rB >= plo && rB < phi){ s_dB = tid; s_cloB = plo; }
            }
            __syncthreads();
            unsigned dA = s_dA, dB = s_dB;
            if (dA != dB){
                unsigned mA = prefMask | (msk << shift);
                unsigned vAp = prefVal | (dA << shift);
                unsigned vBp = prefVal | (dB << shift);
                unsigned locA = 0u, locB = 0xFFFFFFFFu;
                #pragma unroll
                for (int e = 0; e < 32; ++e){
                    if ((key[e] & mA) == vAp) locA = max(locA, key[e]);
                    if ((key[e] & mA) == vBp) locB = min(locB, key[e]);
                }
                #pragma unroll
                for (int o = 32; o > 0; o >>= 1){
                    locA = max(locA, __shfl_down(locA, o));
                    locB = min(locB, __shfl_down(locB, o));
                }
                if (lane == 0){ redA[wid] = locA; redB[wid] = locB; }
                __syncthreads();
                if (tid == 0){
                    unsigned a = redA[0], b = redB[0];
                    for (int w = 1; w < 8; ++w){ a = max(a, redA[w]); b = min(b, redB[w]); }
                    s_keyA = a; s_keyB = b;
                }
                __syncthreads();
                done = true;
            } else {
                prefVal |= dA << shift;
                prefMask |= msk << shift;
                rA -= s_cloA; rB -= s_cloB;
                if (lvl == 2){
                    if (tid == 0){ s_keyA = prefVal; s_keyB = prefVal; }
                    done = true;
                }
                __syncthreads();
            }
        }
    }

    float vlo = key2f(s_keyA);
    float vhi = key2f(s_keyB);
    float idxq = 0.95f * 16383.0f;
    float frac = idxq - floorf(idxq);
    const float thr = vlo * (1.0f - frac) + vhi * frac;

    #pragma unroll
    for (int k = 0; k < 8; ++k){
        int i = tid + k * 512;
        float f0 = key2f(key[4*k+0]); f0 = (f0 >= thr) ? f0 : 0.0f;
        float f1 = key2f(key[4*k+1]); f1 = (f1 >= thr) ? f1 : 0.0f;
        float f2 = key2f(key[4*k+2]); f2 = (f2 >= thr) ? f2 : 0.0f;
        float f3 = key2f(key[4*k+3]); f3 = (f3 >= thr) ? f3 : 0.0f;
        uint2 w; w.x = cvtpk(f0, f1); w.y = cvtpk(f2, f3);
        ((uint2*)C0)[i] = w;
    }
    __syncthreads();

    {
        const unsigned* C0w = (const unsigned*)C0;
        unsigned* outp32 = (unsigned*)(outp + (size_t)bc * HW_);
        const int wc = lane;
        const int r0 = wid * 16;

        unsigned hmA, hmB, hmC, cB, cC;
        {
            int r = r0 - 1;
            if (r < 0){ hmA = 0u; }
            else {
                unsigned w = C0w[r*64 + wc];
                unsigned wl = __shfl_up(w, 1);
                unsigned wr = __shfl_down(w, 1);
                if (wc == 0)  wl = 0u;
                if (wc == 63) wr = 0u;
                hmA = pkmax(pkmax(alignb(w, wl), w), alignb(wr, w));
            }
        }
        {
            int r = r0;
            unsigned w = C0w[r*64 + wc];
            unsigned wl = __shfl_up(w, 1);
            unsigned wr = __shfl_down(w, 1);
            if (wc == 0)  wl = 0u;
            if (wc == 63) wr = 0u;
            hmB = pkmax(pkmax(alignb(w, wl), w), alignb(wr, w));
            cB = w;
        }
        #pragma unroll
        for (int rr = 0; rr < 16; ++rr){
            int r = r0 + rr;
            {
                int rn = r + 1;
                if (rn > 127){ hmC = 0u; cC = 0u; }
                else {
                    unsigned w = C0w[rn*64 + wc];
                    unsigned wl = __shfl_up(w, 1);
                    unsigned wr = __shfl_down(w, 1);
                    if (wc == 0)  wl = 0u;
                    if (wc == 63) wr = 0u;
                    hmC = pkmax(pkmax(alignb(w, wl), w), alignb(wr, w));
                    cC = w;
                }
            }
            unsigned p1 = pkmax(pkmax(hmA, hmB), hmC);
            float a0 = g1 * bf2f((unsigned short)(p1 & 0xFFFFu));
            float a1v = g1 * bf2f((unsigned short)(p1 >> 16));
            outp32[r*64 + wc] = pkmax(cB, cvtpk(a0, a1v));
            unsigned wjm1 = __shfl_up(p1, 1);
            unsigned wjp1 = __shfl_down(p1, 1);
            if (wc == 0)  wjm1 = 0u;
            if (wc == 63) wjp1 = 0u;
            unsigned s = pkmax(wjm1, p1);
            s = pkmax(s, s >> 16);
            s = pkmax(s, wjp1 & 0xFFFFu);
            H5s[r*64 + wc] = (unsigned short)s;
            hmA = hmB; hmB = hmC; cB = cC;
        }
    }
    __syncthreads();

    unsigned* U = (unsigned*)C0;
    unsigned* T = ((unsigned*)C0) + 2048;
    float mf[8];
    #pragma unroll
    for (int k = 0; k < 4; ++k){
        int q = tid + k * 512;
        int i = q >> 5, wj = q & 31;
        int rr = 2 * i;
        const unsigned* H5w = (const unsigned*)H5s;
        unsigned m = pkmax(H5w[rr*32 + wj], H5w[(rr+1)*32 + wj]);
        if (rr >= 1) m = pkmax(m, H5w[(rr-1)*32 + wj]);
        if (rr >= 2) m = pkmax(m, H5w[(rr-2)*32 + wj]);
        if (rr + 2 <= 127) m = pkmax(m, H5w[(rr+2)*32 + wj]);
        U[q] = m;
        mf[2*k]   = q2 * bf2f((unsigned short)(m & 0xFFFFu));
        mf[2*k+1] = q2 * bf2f((unsigned short)(m >> 16));
    }
    __syncthreads();

    const float gs[4] = {q3, q4, q5, q6};
    #pragma unroll
    for (int it = 0; it < 4; ++it){
        #pragma unroll
        for (int k = 0; k < 4; ++k){
            int q = tid + k * 512;
            unsigned w = U[q];
            unsigned wl = __shfl_up(w, 1);
            unsigned wr = __shfl_down(w, 1);
            if ((q & 31) == 0)  wl = 0u;
            if ((q & 31) == 31) wr = 0u;
            T[q] = pkmax(pkmax(alignb(w, wl), w), alignb(wr, w));
        }
        __syncthreads();
        #pragma unroll
        for (int k = 0; k < 4; ++k){
            int q = tid + k * 512;
            int r = q >> 5;
            unsigned w = T[q];
            if (r > 0)  w = pkmax(w, T[q - 32]);
            if (r < 63) w = pkmax(w, T[q + 32]);
            U[q] = w;
            mf[2*k]   = fmaxf(mf[2*k],   gs[it] * bf2f((unsigned short)(w & 0xFFFFu)));
            mf[2*k+1] = fmaxf(mf[2*k+1], gs[it] * bf2f((unsigned short)(w >> 16)));
        }
        __syncthreads();
    }

    {
        unsigned* mp = (unsigned*)(m64g + (size_t)bc * 4096);
        #pragma unroll
        for (int k = 0; k < 4; ++k){
            int q = tid + k * 512;
            mp[q] = cvtpk(mf[2*k], mf[2*k+1]);
        }
    }
}

// ============================ K3: MFMA MLP v4 ============================
// v3 + software-pipelined x prefetch (4-deep circular reg buffer; loads for
// the epilogue issued before staging so HBM latency hides under GEMM1).
__global__ __launch_bounds__(256, 5) void k3_mfma(
    const float* __restrict__ x,
    const unsigned short* __restrict__ outp, const unsigned short* __restrict__ m64,
    const unsigned short* __restrict__ W1h, const unsigned short* __restrict__ W1l,
    const unsigned short* __restrict__ W2h, const unsigned short* __restrict__ W2l,
    const float* __restrict__ b1, const float* __restrict__ b2,
    float* __restrict__ y)
{
    __shared__ __align__(16) unsigned SOUT32[8192];   // [64px][128 ch-pair words], swizzled

    const int tid  = threadIdx.x;
    const int lane = tid & 63;
    const int wid  = tid >> 6;
    const int blk  = blockIdx.x;
    const int b    = blk >> 8;
    const int px0  = (blk & 255) * 64;

    const int nidx = lane & 15;
    const int kg   = lane >> 4;
    const int px_t = wid*16 + nidx;
    const int sxz  = ((px_t >> 1) & 7) << 2;

    // epilogue address helper: iteration t touches ch = t*16+nidx, px += kg*4
    const size_t ebase = (size_t)(b*256 + nidx)*HW_ + px0 + wid*16 + kg*4;

    // ---- x prefetch prologue (issued FIRST; latency hides under staging+GEMM1) ----
    float4 xbuf[4];
    #pragma unroll
    for (int t = 0; t < 4; ++t)
        xbuf[t] = *(const float4*)&x[ebase + (size_t)t*16*HW_];

    // ---- stage out' = max(outp, m64up): repack channel-pairs per px, swizzled ----
    {
        const int row = px0 >> 7;
        const int mibase = (row >> 1)*64 + ((px0 & 127) >> 1);
        const unsigned* op32 = (const unsigned*)(outp + (size_t)b*256*HW_);
        const unsigned short* mp = m64 + (size_t)b*256*4096;
        #pragma unroll
        for (int i = 0; i < 16; ++i){
            int u = i*256 + tid;
            int c4 = u >> 5, pxp = u & 31;       // c4: ch pair 0..127, pxp: px pair 0..31
            int ch0 = 2*c4;
            unsigned wA = op32[ch0*(HW_/2) + px0/2 + pxp];
            unsigned wB = op32[(ch0+1)*(HW_/2) + px0/2 + pxp];
            unsigned mA = (unsigned)mp[ch0*4096 + mibase + pxp] * 0x10001u;
            unsigned mB = (unsigned)mp[(ch0+1)*4096 + mibase + pxp] * 0x10001u;
            unsigned va = pkmax(wA, mA);
            unsigned vb = pkmax(wB, mB);
            unsigned wpa = (va & 0xFFFFu) | (vb << 16);        // (ch0,ch1) @ even px
            unsigned wpb = (va >> 16) | (vb & 0xFFFF0000u);    // (ch0,ch1) @ odd px
            int sw = (pxp & 7) << 2;
            SOUT32[(2*pxp)  *128 + (c4 ^ sw)] = wpa;
            SOUT32[(2*pxp+1)*128 + (c4 ^ sw)] = wpb;
        }
    }
    __syncthreads();

    // ---- GEMM1: D1[mid][px] = (W1hi+W1lo) x out' ----
    f32x4 acc = {0.f, 0.f, 0.f, 0.f};
    #pragma unroll
    for (int ks = 0; ks < 8; ++ks){
        int w0 = (ks*16 + kg*4) ^ sxz;
        bf16x8 fb = tofrag(*(const uint4*)&SOUT32[px_t*128 + w0]);
        bf16x8 ah = tofrag(*(const uint4*)(W1h + nidx*256 + ks*32 + kg*8));
        bf16x8 al = tofrag(*(const uint4*)(W1l + nidx*256 + ks*32 + kg*8));
        acc = __builtin_amdgcn_mfma_f32_16x16x32_bf16(ah, fb, acc, 0, 0, 0);
        acc = __builtin_amdgcn_mfma_f32_16x16x32_bf16(al, fb, acc, 0, 0, 0);
    }

    // ---- relu + bias; hi/lo split; pack to bf16 pairs (this thread: mids kg*4..+4, px=nidx) ----
    float h0 = fmaxf(acc[0] + b1[kg*4 + 0], 0.0f);
    float h1 = fmaxf(acc[1] + b1[kg*4 + 1], 0.0f);
    float h2 = fmaxf(acc[2] + b1[kg*4 + 2], 0.0f);
    float h3 = fmaxf(acc[3] + b1[kg*4 + 3], 0.0f);
    unsigned short e0 = f2bf(h0), e1 = f2bf(h1), e2 = f2bf(h2), e3 = f2bf(h3);
    unsigned Wh0 = (unsigned)e0 | ((unsigned)e1 << 16);
    unsigned Wh1 = (unsigned)e2 | ((unsigned)e3 << 16);
    unsigned Wl0 = cvtpk(h0 - bf2f(e0), h1 - bf2f(e1));
    unsigned Wl1 = cvtpk(h2 - bf2f(e2), h3 - bf2f(e3));

    // ---- A2 frags via shuffle: row px = nidx, k = mids kg*8..+8 (kg<2), else 0 ----
    int s0 = ((kg & 1) << 5) + nidx;
    int s1 = s0 + 16;
    unsigned ah0 = (unsigned)__shfl((int)Wh0, s0);
    unsigned ah1 = (unsigned)__shfl((int)Wh1, s0);
    unsigned ah2 = (unsigned)__shfl((int)Wh0, s1);
    unsigned ah3 = (unsigned)__shfl((int)Wh1, s1);
    unsigned bl0 = (unsigned)__shfl((int)Wl0, s0);
    unsigned bl1 = (unsigned)__shfl((int)Wl1, s0);
    unsigned bl2 = (unsigned)__shfl((int)Wl0, s1);
    unsigned bl3 = (unsigned)__shfl((int)Wl1, s1);
    const bool act = (kg < 2);
    uint4 qah = act ? (uint4){ah0, ah1, ah2, ah3} : (uint4){0u,0u,0u,0u};
    uint4 qal = act ? (uint4){bl0, bl1, bl2, bl3} : (uint4){0u,0u,0u,0u};
    bf16x8 A2h = tofrag(qah), A2l = tofrag(qal);

    // ---- GEMM2 (transposed) + pipelined float4 epilogue ----
    #pragma unroll
    for (int t = 0; t < 16; ++t){
        float4 xv = xbuf[t & 3];
        if (t + 4 < 16)
            xbuf[t & 3] = *(const float4*)&x[ebase + (size_t)(t+4)*16*HW_];

        uint4 qbh = {0u,0u,0u,0u}, qbl = {0u,0u,0u,0u};
        if (act){
            qbh = *(const uint4*)(W2h + (t*16 + nidx)*16 + kg*8);
            qbl = *(const uint4*)(W2l + (t*16 + nidx)*16 + kg*8);
        }
        f32x4 d2 = {0.f, 0.f, 0.f, 0.f};
        d2 = __builtin_amdgcn_mfma_f32_16x16x32_bf16(A2h, tofrag(qbh), d2, 0, 0, 0);
        d2 = __builtin_amdgcn_mfma_f32_16x16x32_bf16(A2l, tofrag(qbh), d2, 0, 0, 0);
        d2 = __builtin_amdgcn_mfma_f32_16x16x32_bf16(A2h, tofrag(qbl), d2, 0, 0, 0);

        int ch = t*16 + nidx;
        float bias = b2[ch];
        size_t rowbase = ebase + (size_t)t*16*HW_;
        float4 yv;
        yv.x = xv.x * (1.0f / (1.0f + __expf(-(d2[0] + bias))));
        yv.y = xv.y * (1.0f / (1.0f + __expf(-(d2[1] + bias))));
        yv.z = xv.z * (1.0f / (1.0f + __expf(-(d2[2] + bias))));
        yv.w = xv.w * (1.0f / (1.0f + __expf(-(d2[3] + bias))));
        *(float4*)&y[rowbase] = yv;
    }
}

extern "C" void kernel_launch(void* const* d_in, const int* in_sizes, int n_in,
                              void* d_out, int out_size, void* d_ws, size_t ws_size,
                              hipStream_t stream) {
    const float* x  = (const float*)d_in[0];
    const float* w1 = (const float*)d_in[1];
    const float* b1 = (const float*)d_in[2];
    const float* w2 = (const float*)d_in[3];
    const float* b2 = (const float*)d_in[4];
    float* y  = (float*)d_out;
    char* ws = (char*)d_ws;

    unsigned short* outp = (unsigned short*)ws;                 // 134 MB
    unsigned short* m64  = (unsigned short*)(ws + 134217728);   // 33.5 MB
    unsigned short* W1h  = (unsigned short*)(ws + 167772160);
    unsigned short* W1l  = W1h + 4096;
    unsigned short* W2h  = W1h + 8192;
    unsigned short* W2l  = W1h + 12288;

    float g1 = 0.99f;
    float q2 = (float)std::pow(0.99, 3.0);
    float q3 = (float)std::pow(0.99, 7.0);
    float q4 = (float)std::pow(0.99, 15.0);
    float q5 = (float)std::pow(0.99, 31.0);
    float q6 = (float)std::pow(0.99, 63.0);

    k0_split<<<32, 256, 0, stream>>>(w1, w2, W1h, W1l, W2h, W2l);
    k1f<<<4096, 512, 0, stream>>>(x, outp, m64, g1, q2, q3, q4, q5, q6);
    k3_mfma<<<4096, 256, 0, stream>>>(x, outp, m64, W1h, W1l, W2h, W2l, b1, b2, y);
}

// Round 13
// 306.203 us; speedup vs baseline: 1.1492x; 1.1427x over previous
//
#include <hip/hip_runtime.h>
#include <cmath>
#include <cfloat>

#define HW_ 16384

__device__ __forceinline__ unsigned f2key(float f){
    unsigned u = __float_as_uint(f);
    return u ^ ((u & 0x80000000u) ? 0xFFFFFFFFu : 0x80000000u);
}
__device__ __forceinline__ float key2f(unsigned k){
    unsigned u = (k & 0x80000000u) ? (k ^ 0x80000000u) : ~k;
    return __uint_as_float(u);
}
__device__ __forceinline__ unsigned short f2bf(float f){
    unsigned u = __float_as_uint(f);
    unsigned r = u + 0x7FFFu + ((u >> 16) & 1u);
    return (unsigned short)(r >> 16);
}
__device__ __forceinline__ float bf2f(unsigned short s){
    return __uint_as_float((unsigned)s << 16);
}
// packed helpers (bf16 pairs in u32; all pooled values >= 0 so u16 order == float order)
__device__ __forceinline__ unsigned pkmax(unsigned a, unsigned b){
    unsigned d;
    asm("v_pk_max_u16 %0, %1, %2" : "=v"(d) : "v"(a), "v"(b));
    return d;
}
__device__ __forceinline__ unsigned alignb(unsigned hi, unsigned lo){
    unsigned d;
    asm("v_alignbit_b32 %0, %1, %2, 16" : "=v"(d) : "v"(hi), "v"(lo));
    return d;
}
__device__ __forceinline__ unsigned cvtpk(float lo, float hi){
    unsigned d;
    asm("v_cvt_pk_bf16_f32 %0, %1, %2" : "=v"(d) : "v"(lo), "v"(hi));
    return d;
}
__device__ __forceinline__ unsigned wscan_incl(unsigned v, int lane){
    #pragma unroll
    for (int o = 1; o < 64; o <<= 1){
        unsigned u = __shfl_up(v, o);
        v += (lane >= o) ? u : 0u;
    }
    return v;
}

// ============================ K0: transpose W1 -> W1T[c][m] (runs once) ============================
__global__ __launch_bounds__(256) void k0_prep(
    const float* __restrict__ w1, float* __restrict__ W1T)
{
    int e = blockIdx.x * 256 + threadIdx.x;   // 0..4095
    int m = e >> 8, c = e & 255;
    W1T[c * 16 + m] = w1[m * 256 + c];
}

// ============================ K1f (unchanged from R8) ============================
__global__ __launch_bounds__(512, 6) void k1f(
    const float* __restrict__ x,
    unsigned short* __restrict__ outp, unsigned short* __restrict__ m64g,
    float g1, float q2, float q3, float q4, float q5, float q6)
{
    __shared__ __align__(16) unsigned short C0[16384];
    __shared__ __align__(16) unsigned short H5s[8192];
    __shared__ unsigned hist[1024];
    __shared__ unsigned wsum[8];
    __shared__ unsigned redA[8], redB[8];
    __shared__ unsigned s_dA, s_dB, s_cloA, s_cloB, s_keyA, s_keyB;

    const int tid = threadIdx.x;
    const int lane = tid & 63;
    const int wid = tid >> 6;
    const unsigned bc = blockIdx.x;
    const float4* xp4 = (const float4*)(x + (size_t)bc * HW_);

    unsigned key[32];

    #pragma unroll
    for (int k = 0; k < 2; ++k) hist[tid + k * 512] = 0u;
    __syncthreads();
    #pragma unroll
    for (int k = 0; k < 8; ++k){
        float4 v = xp4[tid + k * 512];
        key[4*k+0] = f2key(v.x);
        key[4*k+1] = f2key(v.y);
        key[4*k+2] = f2key(v.z);
        key[4*k+3] = f2key(v.w);
        atomicAdd(&hist[key[4*k+0] >> 22], 1u);
        atomicAdd(&hist[key[4*k+1] >> 22], 1u);
        atomicAdd(&hist[key[4*k+2] >> 22], 1u);
        atomicAdd(&hist[key[4*k+3] >> 22], 1u);
    }
    __syncthreads();

    unsigned rA = 15563u, rB = 15564u;
    unsigned prefVal = 0u, prefMask = 0u;
    bool done = false;

    {
        unsigned part = hist[tid*2] + hist[tid*2+1];
        unsigned incl = wscan_incl(part, lane);
        if (lane == 63) wsum[wid] = incl;
        __syncthreads();
        unsigned off = 0;
        #pragma unroll
        for (int w = 0; w < 8; ++w) off += (w < wid) ? wsum[w] : 0u;
        unsigned phi = incl + off;
        unsigned plo = phi - part;
        if (rA >= plo && rA < phi){
            unsigned c = plo;
            #pragma unroll
            for (int k = 0; k < 2; ++k){
                unsigned hh = hist[tid*2+k];
                if (rA < c + hh){ s_dA = tid*2+k; s_cloA = c; break; }
                c += hh;
            }
        }
        if (rB >= plo && rB < phi){
            unsigned c = plo;
            #pragma unroll
            for (int k = 0; k < 2; ++k){
                unsigned hh = hist[tid*2+k];
                if (rB < c + hh){ s_dB = tid*2+k; s_cloB = c; break; }
                c += hh;
            }
        }
        __syncthreads();
        unsigned dA = s_dA, dB = s_dB;
        if (dA != dB){
            unsigned locA = 0u, locB = 0xFFFFFFFFu;
            #pragma unroll
            for (int e = 0; e < 32; ++e){
                unsigned d = key[e] >> 22;
                if (d == dA) locA = max(locA, key[e]);
                if (d == dB) locB = min(locB, key[e]);
            }
            #pragma unroll
            for (int o = 32; o > 0; o >>= 1){
                locA = max(locA, __shfl_down(locA, o));
                locB = min(locB, __shfl_down(locB, o));
            }
            if (lane == 0){ redA[wid] = locA; redB[wid] = locB; }
            __syncthreads();
            if (tid == 0){
                unsigned a = redA[0], b = redB[0];
                for (int w = 1; w < 8; ++w){ a = max(a, redA[w]); b = min(b, redB[w]); }
                s_keyA = a; s_keyB = b;
            }
            __syncthreads();
            done = true;
        } else {
            prefVal = dA << 22; prefMask = 0x3FFu << 22;
            rA -= s_cloA; rB -= s_cloB;
            __syncthreads();
        }
    }

    if (!done){
        const int shifts[3] = {14, 6, 0};
        const int bitsv[3]  = {8, 8, 6};
        for (int lvl = 0; lvl < 3 && !done; ++lvl){
            int shift = shifts[lvl];
            unsigned nb = 1u << bitsv[lvl];
            unsigned msk = nb - 1u;
            if (tid < (int)nb) hist[tid] = 0u;
            __syncthreads();
            #pragma unroll
            for (int e = 0; e < 32; ++e){
                if ((key[e] & prefMask) == prefVal)
                    atomicAdd(&hist[(key[e] >> shift) & msk], 1u);
            }
            __syncthreads();
            unsigned part = (tid < (int)nb) ? hist[tid] : 0u;
            unsigned incl = wscan_incl(part, lane);
            if (lane == 63) wsum[wid] = incl;
            __syncthreads();
            unsigned off = 0;
            #pragma unroll
            for (int w = 0; w < 8; ++w) off += (w < wid) ? wsum[w] : 0u;
            unsigned phi = incl + off;
            unsigned plo = phi - part;
            if (tid < (int)nb){
                if (rA >= plo && rA < phi){ s_dA = tid; s_cloA = plo; }
                if (rB >= plo && rB < phi){ s_dB = tid; s_cloB = plo; }
            }
            __syncthreads();
            unsigned dA = s_dA, dB = s_dB;
            if (dA != dB){
                unsigned mA = prefMask | (msk << shift);
                unsigned vAp = prefVal | (dA << shift);
                unsigned vBp = prefVal | (dB << shift);
                unsigned locA = 0u, locB = 0xFFFFFFFFu;
                #pragma unroll
                for (int e = 0; e < 32; ++e){
                    if ((key[e] & mA) == vAp) locA = max(locA, key[e]);
                    if ((key[e] & mA) == vBp) locB = min(locB, key[e]);
                }
                #pragma unroll
                for (int o = 32; o > 0; o >>= 1){
                    locA = max(locA, __shfl_down(locA, o));
                    locB = min(locB, __shfl_down(locB, o));
                }
                if (lane == 0){ redA[wid] = locA; redB[wid] = locB; }
                __syncthreads();
                if (tid == 0){
                    unsigned a = redA[0], b = redB[0];
                    for (int w = 1; w < 8; ++w){ a = max(a, redA[w]); b = min(b, redB[w]); }
                    s_keyA = a; s_keyB = b;
                }
                __syncthreads();
                done = true;
            } else {
                prefVal |= dA << shift;
                prefMask |= msk << shift;
                rA -= s_cloA; rB -= s_cloB;
                if (lvl == 2){
                    if (tid == 0){ s_keyA = prefVal; s_keyB = prefVal; }
                    done = true;
                }
                __syncthreads();
            }
        }
    }

    float vlo = key2f(s_keyA);
    float vhi = key2f(s_keyB);
    float idxq = 0.95f * 16383.0f;
    float frac = idxq - floorf(idxq);
    const float thr = vlo * (1.0f - frac) + vhi * frac;

    #pragma unroll
    for (int k = 0; k < 8; ++k){
        int i = tid + k * 512;
        float f0 = key2f(key[4*k+0]); f0 = (f0 >= thr) ? f0 : 0.0f;
        float f1 = key2f(key[4*k+1]); f1 = (f1 >= thr) ? f1 : 0.0f;
        float f2 = key2f(key[4*k+2]); f2 = (f2 >= thr) ? f2 : 0.0f;
        float f3 = key2f(key[4*k+3]); f3 = (f3 >= thr) ? f3 : 0.0f;
        uint2 w; w.x = cvtpk(f0, f1); w.y = cvtpk(f2, f3);
        ((uint2*)C0)[i] = w;
    }
    __syncthreads();

    {
        const unsigned* C0w = (const unsigned*)C0;
        unsigned* outp32 = (unsigned*)(outp + (size_t)bc * HW_);
        const int wc = lane;
        const int r0 = wid * 16;

        unsigned hmA, hmB, hmC, cB, cC;
        {
            int r = r0 - 1;
            if (r < 0){ hmA = 0u; }
            else {
                unsigned w = C0w[r*64 + wc];
                unsigned wl = __shfl_up(w, 1);
                unsigned wr = __shfl_down(w, 1);
                if (wc == 0)  wl = 0u;
                if (wc == 63) wr = 0u;
                hmA = pkmax(pkmax(alignb(w, wl), w), alignb(wr, w));
            }
        }
        {
            int r = r0;
            unsigned w = C0w[r*64 + wc];
            unsigned wl = __shfl_up(w, 1);
            unsigned wr = __shfl_down(w, 1);
            if (wc == 0)  wl = 0u;
            if (wc == 63) wr = 0u;
            hmB = pkmax(pkmax(alignb(w, wl), w), alignb(wr, w));
            cB = w;
        }
        #pragma unroll
        for (int rr = 0; rr < 16; ++rr){
            int r = r0 + rr;
            {
                int rn = r + 1;
                if (rn > 127){ hmC = 0u; cC = 0u; }
                else {
                    unsigned w = C0w[rn*64 + wc];
                    unsigned wl = __shfl_up(w, 1);
                    unsigned wr = __shfl_down(w, 1);
                    if (wc == 0)  wl = 0u;
                    if (wc == 63) wr = 0u;
                    hmC = pkmax(pkmax(alignb(w, wl), w), alignb(wr, w));
                    cC = w;
                }
            }
            unsigned p1 = pkmax(pkmax(hmA, hmB), hmC);
            float a0 = g1 * bf2f((unsigned short)(p1 & 0xFFFFu));
            float a1v = g1 * bf2f((unsigned short)(p1 >> 16));
            outp32[r*64 + wc] = pkmax(cB, cvtpk(a0, a1v));
            unsigned wjm1 = __shfl_up(p1, 1);
            unsigned wjp1 = __shfl_down(p1, 1);
            if (wc == 0)  wjm1 = 0u;
            if (wc == 63) wjp1 = 0u;
            unsigned s = pkmax(wjm1, p1);
            s = pkmax(s, s >> 16);
            s = pkmax(s, wjp1 & 0xFFFFu);
            H5s[r*64 + wc] = (unsigned short)s;
            hmA = hmB; hmB = hmC; cB = cC;
        }
    }
    __syncthreads();

    unsigned* U = (unsigned*)C0;
    unsigned* T = ((unsigned*)C0) + 2048;
    float mf[8];
    #pragma unroll
    for (int k = 0; k < 4; ++k){
        int q = tid + k * 512;
        int i = q >> 5, wj = q & 31;
        int rr = 2 * i;
        const unsigned* H5w = (const unsigned*)H5s;
        unsigned m = pkmax(H5w[rr*32 + wj], H5w[(rr+1)*32 + wj]);
        if (rr >= 1) m = pkmax(m, H5w[(rr-1)*32 + wj]);
        if (rr >= 2) m = pkmax(m, H5w[(rr-2)*32 + wj]);
        if (rr + 2 <= 127) m = pkmax(m, H5w[(rr+2)*32 + wj]);
        U[q] = m;
        mf[2*k]   = q2 * bf2f((unsigned short)(m & 0xFFFFu));
        mf[2*k+1] = q2 * bf2f((unsigned short)(m >> 16));
    }
    __syncthreads();

    const float gs[4] = {q3, q4, q5, q6};
    #pragma unroll
    for (int it = 0; it < 4; ++it){
        #pragma unroll
        for (int k = 0; k < 4; ++k){
            int q = tid + k * 512;
            unsigned w = U[q];
            unsigned wl = __shfl_up(w, 1);
            unsigned wr = __shfl_down(w, 1);
            if ((q & 31) == 0)  wl = 0u;
            if ((q & 31) == 31) wr = 0u;
            T[q] = pkmax(pkmax(alignb(w, wl), w), alignb(wr, w));
        }
        __syncthreads();
        #pragma unroll
        for (int k = 0; k < 4; ++k){
            int q = tid + k * 512;
            int r = q >> 5;
            unsigned w = T[q];
            if (r > 0)  w = pkmax(w, T[q - 32]);
            if (r < 63) w = pkmax(w, T[q + 32]);
            U[q] = w;
            mf[2*k]   = fmaxf(mf[2*k],   gs[it] * bf2f((unsigned short)(w & 0xFFFFu)));
            mf[2*k+1] = fmaxf(mf[2*k+1], gs[it] * bf2f((unsigned short)(w >> 16)));
        }
        __syncthreads();
    }

    {
        unsigned* mp = (unsigned*)(m64g + (size_t)bc * 4096);
        #pragma unroll
        for (int k = 0; k < 4; ++k){
            int q = tid + k * 512;
            mp[q] = cvtpk(mf[2*k], mf[2*k+1]);
        }
    }
}

// ============================ K3: scalar MLP, SGPR weights, zero LDS ============================
// 1 px/thread, 1024 blocks. Weight rows W1T[c][0:16] / w2[c][0:16] and b2[c]
// are wave-uniform -> compiler emits s_load; FMAs are v_fmac(v, s, v).
// No LDS, no barrier. Same arithmetic as R8 scalar k3 (absmax-identical).
__global__ __launch_bounds__(256, 6) void k3_sgpr(
    const float* __restrict__ x,
    const unsigned short* __restrict__ outp, const unsigned short* __restrict__ m64,
    const float* __restrict__ W1T,   // [256][16] f32 (w1 transposed)
    const float* __restrict__ w2,    // [256][16] f32
    const float* __restrict__ b1, const float* __restrict__ b2,
    float* __restrict__ y)
{
    const int tid = threadIdx.x;
    const int blk = blockIdx.x;
    const int b = blk >> 6;
    const int t = blk & 63;

    const int pix = t * 256 + tid;
    const int mi = (pix >> 8) * 64 + ((pix & 127) >> 1);
    const size_t base = (size_t)b * 256 * HW_;
    const size_t mbase = (size_t)b * 256 * 4096;

    float h[16];
    #pragma unroll
    for (int m = 0; m < 16; ++m) h[m] = 0.0f;

    #pragma unroll 4
    for (int c = 0; c < 256; ++c){
        float o  = bf2f(outp[base + (size_t)c * HW_ + pix]);
        float mo = bf2f(m64[mbase + (size_t)c * 4096 + mi]);
        o = fmaxf(o, mo);
        const float4* wr = (const float4*)(W1T + c * 16);   // uniform -> s_load
        float4 a0 = wr[0], a1 = wr[1], a2 = wr[2], a3 = wr[3];
        h[0]  = fmaf(a0.x, o, h[0]);  h[1]  = fmaf(a0.y, o, h[1]);
        h[2]  = fmaf(a0.z, o, h[2]);  h[3]  = fmaf(a0.w, o, h[3]);
        h[4]  = fmaf(a1.x, o, h[4]);  h[5]  = fmaf(a1.y, o, h[5]);
        h[6]  = fmaf(a1.z, o, h[6]);  h[7]  = fmaf(a1.w, o, h[7]);
        h[8]  = fmaf(a2.x, o, h[8]);  h[9]  = fmaf(a2.y, o, h[9]);
        h[10] = fmaf(a2.z, o, h[10]); h[11] = fmaf(a2.w, o, h[11]);
        h[12] = fmaf(a3.x, o, h[12]); h[13] = fmaf(a3.y, o, h[13]);
        h[14] = fmaf(a3.z, o, h[14]); h[15] = fmaf(a3.w, o, h[15]);
    }
    #pragma unroll
    for (int m = 0; m < 16; ++m) h[m] = fmaxf(h[m] + b1[m], 0.0f);

    #pragma unroll 4
    for (int c = 0; c < 256; ++c){
        const float4* wr = (const float4*)(w2 + c * 16);    // uniform -> s_load
        float4 a0 = wr[0], a1 = wr[1], a2 = wr[2], a3 = wr[3];
        float acc = b2[c];
        acc += a0.x * h[0]  + a0.y * h[1]  + a0.z * h[2]  + a0.w * h[3];
        acc += a1.x * h[4]  + a1.y * h[5]  + a1.z * h[6]  + a1.w * h[7];
        acc += a2.x * h[8]  + a2.y * h[9]  + a2.z * h[10] + a2.w * h[11];
        acc += a3.x * h[12] + a3.y * h[13] + a3.z * h[14] + a3.w * h[15];
        float R = 1.0f / (1.0f + __expf(-acc));
        float xv = x[base + (size_t)c * HW_ + pix];
        y[base + (size_t)c * HW_ + pix] = xv * R;
    }
}

extern "C" void kernel_launch(void* const* d_in, const int* in_sizes, int n_in,
                              void* d_out, int out_size, void* d_ws, size_t ws_size,
                              hipStream_t stream) {
    const float* x  = (const float*)d_in[0];
    const float* w1 = (const float*)d_in[1];
    const float* b1 = (const float*)d_in[2];
    const float* w2 = (const float*)d_in[3];
    const float* b2 = (const float*)d_in[4];
    float* y  = (float*)d_out;
    char* ws = (char*)d_ws;

    unsigned short* outp = (unsigned short*)ws;                 // 134 MB
    unsigned short* m64  = (unsigned short*)(ws + 134217728);   // 33.5 MB
    float*          W1T  = (float*)(ws + 167772160);            // 16 KB

    float g1 = 0.99f;
    float q2 = (float)std::pow(0.99, 3.0);
    float q3 = (float)std::pow(0.99, 7.0);
    float q4 = (float)std::pow(0.99, 15.0);
    float q5 = (float)std::pow(0.99, 31.0);
    float q6 = (float)std::pow(0.99, 63.0);

    k0_prep<<<16, 256, 0, stream>>>(w1, W1T);
    k1f<<<4096, 512, 0, stream>>>(x, outp, m64, g1, q2, q3, q4, q5, q6);
    k3_sgpr<<<1024, 256, 0, stream>>>(x, outp, m64, W1T, w2, b1, b2, y);
}